// Round 8
// baseline (506.533 us; speedup 1.0000x reference)
//
#include <hip/hip_runtime.h>
#include <hip/hip_bf16.h>
#include <math.h>

// Problem constants (from reference setup_inputs)
#define BN  8
#define QN  2048
#define KN  2048
#define FN  512
#define FVN 512

typedef __bf16 bf16x8 __attribute__((ext_vector_type(8)));
typedef __bf16 bf16x4v __attribute__((ext_vector_type(4)));
typedef float  f32x4  __attribute__((ext_vector_type(4)));

__device__ inline bf16x8 pack8(float4 a, float4 b) {
  bf16x8 r;
  r[0] = (__bf16)a.x; r[1] = (__bf16)a.y; r[2] = (__bf16)a.z; r[3] = (__bf16)a.w;
  r[4] = (__bf16)b.x; r[5] = (__bf16)b.y; r[6] = (__bf16)b.z; r[7] = (__bf16)b.w;
  return r;
}

// Async global->LDS, 16B/lane. LDS dest = wave-uniform base + lane*16 (m97).
__device__ __forceinline__ void g2l16(const __bf16* g, __bf16* l) {
  __builtin_amdgcn_global_load_lds(
      (const __attribute__((address_space(1))) void*)g,
      (__attribute__((address_space(3))) void*)l,
      16, 0, 0);
}
__device__ __forceinline__ void g2l16v(const void* g, void* l) {
  __builtin_amdgcn_global_load_lds(
      (const __attribute__((address_space(1))) void*)g,
      (__attribute__((address_space(3))) void*)l,
      16, 0, 0);
}

// ---------------------------------------------------------------------------
// Kernel 0 (prep): y==0 -> q convert (pre-scaled), y==1 -> k convert,
//                  y==2 -> v transpose to Vt[b, fv, k] bf16, y==3 -> zero sums.
// ---------------------------------------------------------------------------
__global__ __launch_bounds__(256) void prep(
    const float* __restrict__ qm, const float* __restrict__ km,
    const float* __restrict__ vm,
    __bf16* __restrict__ qb, __bf16* __restrict__ kb, __bf16* __restrict__ Vt,
    float* __restrict__ sums) {
  const int tid = threadIdx.x;
  if (blockIdx.y == 0) {
    const size_t idx = ((size_t)blockIdx.x * 256 + tid) * 8;
    const float scale = 0.044194173824159216f;  // 512^-0.5
    float4 a = *(const float4*)(qm + idx);
    float4 b = *(const float4*)(qm + idx + 4);
    a.x *= scale; a.y *= scale; a.z *= scale; a.w *= scale;
    b.x *= scale; b.y *= scale; b.z *= scale; b.w *= scale;
    *(bf16x8*)(qb + idx) = pack8(a, b);
  } else if (blockIdx.y == 1) {
    const size_t idx = ((size_t)blockIdx.x * 256 + tid) * 8;
    float4 a = *(const float4*)(km + idx);
    float4 b = *(const float4*)(km + idx + 4);
    *(bf16x8*)(kb + idx) = pack8(a, b);
  } else if (blockIdx.y == 2) {
    // v transpose: 2048 logical blocks; bx = ((b*8)+fblk)*32 + kblk
    const int bx = blockIdx.x;
    if (bx >= (KN / 64) * (FVN / 64) * BN) return;
    const int b  = bx >> 8;                 // /(32*8)
    const int f0 = ((bx >> 5) & 7) * 64;
    const int k0 = (bx & 31) * 64;
    __shared__ float tile[64][65];
    const int r = tid >> 4;          // 0..15
    const int c = (tid & 15) * 4;    // 0..60
#pragma unroll
    for (int i = 0; i < 4; i++) {
      float4 u = *(const float4*)(vm + ((size_t)b * KN + k0 + r + i * 16) * FVN + f0 + c);
      tile[r + i * 16][c] = u.x; tile[r + i * 16][c + 1] = u.y;
      tile[r + i * 16][c + 2] = u.z; tile[r + i * 16][c + 3] = u.w;
    }
    __syncthreads();
#pragma unroll
    for (int i = 0; i < 4; i++) {
      int fv = r + i * 16;
      bf16x4v w;
      w[0] = (__bf16)tile[c][fv];     w[1] = (__bf16)tile[c + 1][fv];
      w[2] = (__bf16)tile[c + 2][fv]; w[3] = (__bf16)tile[c + 3][fv];
      *(bf16x4v*)(Vt + ((size_t)b * FVN + f0 + fv) * KN + k0 + c) = w;
    }
  } else {
    // zero sums[BN*QN] f32 = 64 KB: 16 blocks x 256 thr x 16B
    if (blockIdx.x < (BN * QN) / 1024) {
      float4 z4; z4.x = 0.f; z4.y = 0.f; z4.z = 0.f; z4.w = 0.f;
      ((float4*)sums)[(size_t)blockIdx.x * 256 + tid] = z4;
    }
  }
}

// ---------------------------------------------------------------------------
// Kernel 1: S[z,q,k] = (bf16) dot(qb[b,q,:], kb[b,k,:])   (scale pre-folded)
// 128x128 tile, BK=64 as two m97-verified [128][32] LDS half-tiles.
// Epilogue accumulates row-sums of exp(S) into sums[b,q]. [verified r1-r7]
// NEW (r8): L3-warm mask prefetch — each block pulls its own (batch,128q,128k)
// slice of attn+alibi through L2/L3 via g2l16 into a 1KB garbage LDS buffer
// (no VGPR landing space, hidden under the MFMA phase; issued post-drain so
// completion folds into the NEXT iteration's barrier). Reverse-batch mapping
// (bpre = last-z) so the freshest-warmed batch is the first softmax_w reads.
// Coverage: 2048 blocks x 8 iters x 16 rows x 128 cols x 2 masks = 268 MB,
// each element exactly once.
// ---------------------------------------------------------------------------
__global__ __launch_bounds__(256) void gemm_s(
    const __bf16* __restrict__ qb, const __bf16* __restrict__ kb,
    __bf16* __restrict__ Sws, float* __restrict__ sums,
    const int* __restrict__ attn, const int* __restrict__ alibi,
    int b0, int q0, int qchunk) {
  __shared__ __align__(16) __bf16 As[2][128][32];  // 16 KB, k-half h
  __shared__ __align__(16) __bf16 Bs[2][128][32];
  __shared__ __align__(16) __bf16 junk[512];       // 1 KB garbage g2l dest
  const int tid = threadIdx.x;
  const int lane = tid & 63, wave = tid >> 6;
  const int wq = (wave & 1) * 64, wk = (wave >> 1) * 64;
  const int qt = blockIdx.x * 128, kt = blockIdx.y * 128;
  const int z = blockIdx.z, b = b0 + z;
  __bf16* S = Sws + (size_t)z * qchunk * KN;
  const __bf16* Ab = qb + ((size_t)b * QN + q0 + qt) * FN;
  const __bf16* Bb = kb + ((size_t)b * KN + kt) * FN;
  const int srow = lane >> 2;         // 0..15 within 16-row group
  const int scol = (lane & 3) * 8;    // bf16 col within 32
  const int r = lane & 15, quad = lane >> 4;
  // prefetch addressing (per-lane global src is allowed for g2l)
  const int bpre = b0 + ((int)gridDim.z - 1 - z);
  const size_t rbp = (size_t)bpre * QN;
  const int pcc = kt + (lane & 31) * 4;   // 32 lanes x 4 ints = 128 cols
  const int pr2 = lane >> 5;              // 2 rows per instruction
  f32x4 acc[4][4] = {};
  for (int f0 = 0; f0 < FN; f0 += 64) {
    __syncthreads();                  // prev-iter frag reads done
#pragma unroll
    for (int h = 0; h < 2; h++) {
      const int co = f0 + h * 32 + scol;
      g2l16(Ab + (size_t)(wave * 32 + srow) * FN + co,      &As[h][wave * 32][0]);
      g2l16(Ab + (size_t)(wave * 32 + 16 + srow) * FN + co, &As[h][wave * 32 + 16][0]);
      g2l16(Bb + (size_t)(wave * 32 + srow) * FN + co,      &Bs[h][wave * 32][0]);
      g2l16(Bb + (size_t)(wave * 32 + 16 + srow) * FN + co, &Bs[h][wave * 32 + 16][0]);
    }
    __syncthreads();                  // vmcnt drain + visibility
    {  // --- L3-warm mask prefetch: 16 rows x 128 cols x 2 masks this iter ---
      const int pr = q0 + qt + (f0 >> 6) * 16 + wave * 4;
      g2l16v(attn  + (rbp + pr + pr2) * KN + pcc,     junk);
      g2l16v(attn  + (rbp + pr + 2 + pr2) * KN + pcc, junk);
      g2l16v(alibi + (rbp + pr + pr2) * KN + pcc,     junk);
      g2l16v(alibi + (rbp + pr + 2 + pr2) * KN + pcc, junk);
    }
#pragma unroll
    for (int h = 0; h < 2; h++) {
      bf16x8 af[4], bf[4];
#pragma unroll
      for (int i = 0; i < 4; i++) af[i] = *(bf16x8*)&As[h][wq + i * 16 + r][quad * 8];
#pragma unroll
      for (int j = 0; j < 4; j++) bf[j] = *(bf16x8*)&Bs[h][wk + j * 16 + r][quad * 8];
#pragma unroll
      for (int i = 0; i < 4; i++)
#pragma unroll
        for (int j = 0; j < 4; j++)
          acc[i][j] = __builtin_amdgcn_mfma_f32_16x16x32_bf16(af[i], bf[j], acc[i][j], 0, 0, 0);
    }
  }
  // C/D layout (m89-verified): col = lane&15 (=k), row = quad*4+reg (=q)
#pragma unroll
  for (int i = 0; i < 4; i++)
#pragma unroll
    for (int j = 0; j < 4; j++)
#pragma unroll
      for (int t = 0; t < 4; t++) {
        int qq = qt + wq + i * 16 + quad * 4 + t;
        int kk = kt + wk + j * 16 + r;
        S[(size_t)qq * KN + kk] = (__bf16)acc[i][j][t];
      }
  // Row-sum of exp over this block's 64 k-cols per wave (denominator is
  // UNMASKED sum over all k; partials from the 16 kt-blocks accumulate).
#pragma unroll
  for (int i = 0; i < 4; i++)
#pragma unroll
    for (int t = 0; t < 4; t++) {
      float part = 0.f;
#pragma unroll
      for (int j = 0; j < 4; j++) part += __expf(acc[i][j][t]);
      part += __shfl_xor(part, 1);
      part += __shfl_xor(part, 2);
      part += __shfl_xor(part, 4);
      part += __shfl_xor(part, 8);
      if (r == 0)
        atomicAdd(&sums[(size_t)b * QN + q0 + qt + wq + i * 16 + quad * 4 + t], part);
    }
}

// ---------------------------------------------------------------------------
// Kernel 2: in-place W = attn ? 0 : (exp(S)*inv - (alibi ? 0 : dist*bs))
// One q-row per block (256 thr) — EXACT r3-verified version (77.5 us, 80% occ).
// S + both masks staged via global_load_lds (deep vmcnt queue, no VGPR cap).
// Masks should now be L3-resident from gemm_s's prefetch.
// ---------------------------------------------------------------------------
__global__ __launch_bounds__(256) void softmax_w(
    __bf16* __restrict__ Sws,
    const float* __restrict__ cq, const float* __restrict__ ck,
    const int* __restrict__ attn, const int* __restrict__ alibi,
    const float* __restrict__ bsp, const float* __restrict__ sums,
    int b0, int q0, int qchunk) {
  __shared__ __align__(16) __bf16 S_lds[KN];   // 4 KB
  __shared__ __align__(16) int    am_lds[KN];  // 8 KB
  __shared__ __align__(16) int    al_lds[KN];  // 8 KB
  const int tid = threadIdx.x;
  const int lane = tid & 63, wave = tid >> 6;
  const int z = blockIdx.z, b = b0 + z;
  const int ql = blockIdx.x;              // local q row in chunk
  const int qg = q0 + ql;                 // global q
  __bf16* Srow = Sws + ((size_t)z * qchunk + ql) * KN;
  const int* arow = attn + ((size_t)b * QN + qg) * KN;
  const int* lrow = alibi + ((size_t)b * QN + qg) * KN;
  const float* ckb = ck + (size_t)b * KN * 2;
  // --- stage S (4x1KB) + attn (8x1KB) + alibi (8x1KB) via g2l16 ---
  // wave w: S seg w; attn segs w, w+4; alibi segs w, w+4  => 5 g2l/wave
  g2l16v((const char*)Srow + wave * 1024 + lane * 16,
         (char*)S_lds + wave * 1024);
#pragma unroll
  for (int s = 0; s < 2; s++) {
    const int seg = wave + s * 4;
    g2l16v((const char*)arow + seg * 1024 + lane * 16, (char*)am_lds + seg * 1024);
    g2l16v((const char*)lrow + seg * 1024 + lane * 16, (char*)al_lds + seg * 1024);
  }
  // --- per-thread coord loads (global, L2-hot) + uniform scalars ---
  const int k0g = tid * 4;            // group 0 k-base
  const int k1g = 1024 + tid * 4;     // group 1 k-base
  float4 c00 = *(const float4*)(ckb + (size_t)k0g * 2);
  float4 c01 = *(const float4*)(ckb + (size_t)k0g * 2 + 4);
  float4 c10 = *(const float4*)(ckb + (size_t)k1g * 2);
  float4 c11 = *(const float4*)(ckb + (size_t)k1g * 2 + 4);
  const float inv = 1.0f / sums[(size_t)b * QN + qg];
  const float qx = cq[((size_t)b * QN + qg) * 2 + 0];
  const float qy = cq[((size_t)b * QN + qg) * 2 + 1];
  const float bs = bsp[0];
  __syncthreads();   // drains vmcnt(0) + lgkmcnt(0), then barrier
  // --- consume: 2 groups of 4 contiguous k per thread ---
#pragma unroll
  for (int g = 0; g < 2; g++) {
    const int k = g ? k1g : k0g;
    bf16x4v s4 = *(const bf16x4v*)((const char*)S_lds + (size_t)k * 2);
    int4 am4 = *(const int4*)&am_lds[k];
    int4 al4 = *(const int4*)&al_lds[k];
    float4 ca = g ? c10 : c00;
    float4 cb = g ? c11 : c01;
    float kx[4] = {ca.x, ca.z, cb.x, cb.z};
    float ky[4] = {ca.y, ca.w, cb.y, cb.w};
    int amv[4] = {am4.x, am4.y, am4.z, am4.w};
    int alv[4] = {al4.x, al4.y, al4.z, al4.w};
    bf16x4v w4;
#pragma unroll
    for (int j = 0; j < 4; j++) {
      float p = __expf((float)s4[j]) * inv;
      float dx = qx - kx[j], dy = qy - ky[j];
      float sd = alv[j] ? 0.f : sqrtf(dx * dx + dy * dy) * bs;
      w4[j] = (__bf16)(amv[j] ? 0.f : (p - sd));
    }
    *(bf16x4v*)(Srow + k) = w4;
  }
}

// ---------------------------------------------------------------------------
// Kernel 3: out[b,q,fv] = sum_k W[q,k] * Vt[fv,k] — bf16 GEMM, BK=64.
// ---------------------------------------------------------------------------
__global__ __launch_bounds__(256) void gemm_w(
    const __bf16* __restrict__ W, const __bf16* __restrict__ Vt,
    float* __restrict__ out, int b0, int q0, int qchunk) {
  __shared__ __align__(16) __bf16 As[2][128][32];  // [q][k]
  __shared__ __align__(16) __bf16 Bs[2][128][32];  // [fv][k]
  const int tid = threadIdx.x;
  const int lane = tid & 63, wave = tid >> 6;
  const int wq = (wave & 1) * 64, wf = (wave >> 1) * 64;
  const int qt = blockIdx.x * 128, ft = blockIdx.y * 128;
  const int z = blockIdx.z, b = b0 + z;
  const __bf16* Ab = W + ((size_t)z * qchunk + qt) * KN;
  const __bf16* Bb = Vt + ((size_t)b * FVN + ft) * KN;
  const int srow = lane >> 2;
  const int scol = (lane & 3) * 8;
  const int r = lane & 15, quad = lane >> 4;
  f32x4 acc[4][4] = {};
  for (int k0 = 0; k0 < KN; k0 += 64) {
    __syncthreads();
#pragma unroll
    for (int h = 0; h < 2; h++) {
      const int co = k0 + h * 32 + scol;
      g2l16(Ab + (size_t)(wave * 32 + srow) * KN + co,      &As[h][wave * 32][0]);
      g2l16(Ab + (size_t)(wave * 32 + 16 + srow) * KN + co, &As[h][wave * 32 + 16][0]);
      g2l16(Bb + (size_t)(wave * 32 + srow) * KN + co,      &Bs[h][wave * 32][0]);
      g2l16(Bb + (size_t)(wave * 32 + 16 + srow) * KN + co, &Bs[h][wave * 32 + 16][0]);
    }
    __syncthreads();
#pragma unroll
    for (int h = 0; h < 2; h++) {
      bf16x8 af[4], bf[4];
#pragma unroll
      for (int i = 0; i < 4; i++) af[i] = *(bf16x8*)&As[h][wq + i * 16 + r][quad * 8];
#pragma unroll
      for (int j = 0; j < 4; j++) bf[j] = *(bf16x8*)&Bs[h][wf + j * 16 + r][quad * 8];
#pragma unroll
      for (int i = 0; i < 4; i++)
#pragma unroll
        for (int j = 0; j < 4; j++)
          acc[i][j] = __builtin_amdgcn_mfma_f32_16x16x32_bf16(af[i], bf[j], acc[i][j], 0, 0, 0);
    }
  }
#pragma unroll
  for (int i = 0; i < 4; i++)
#pragma unroll
    for (int j = 0; j < 4; j++)
#pragma unroll
      for (int t = 0; t < 4; t++) {
        int qq = q0 + qt + wq + i * 16 + quad * 4 + t;
        int fv = ft + wf + j * 16 + r;
        out[((size_t)b * QN + qq) * FVN + fv] = acc[i][j][t];
      }
}

// ---------------------------------------------------------------------------
extern "C" void kernel_launch(void* const* d_in, const int* in_sizes, int n_in,
                              void* d_out, int out_size, void* d_ws, size_t ws_size,
                              hipStream_t stream) {
  (void)in_sizes; (void)n_in; (void)out_size;
  const float* qm   = (const float*)d_in[0];
  const float* km   = (const float*)d_in[1];
  const float* vm   = (const float*)d_in[2];
  const float* cq   = (const float*)d_in[3];
  const float* ck   = (const float*)d_in[4];
  const int*   attn = (const int*)d_in[5];
  const int*   alibi= (const int*)d_in[6];
  const float* bsp  = (const float*)d_in[7];
  float* out = (float*)d_out;

  // ws layout: [qb][kb][Vt][sums f32] fixed + [S/W: nb*qc*KN bf16]
  __bf16* qb  = (__bf16*)d_ws;
  __bf16* kb  = qb + (size_t)BN * QN * FN;
  __bf16* Vt  = kb + (size_t)BN * KN * FN;
  float*  sums = (float*)(Vt + (size_t)BN * FVN * KN);
  __bf16* Sws = (__bf16*)(sums + (size_t)BN * QN);
  const size_t fixed = ((size_t)BN * QN * FN + (size_t)BN * KN * FN +
                        (size_t)BN * FVN * KN) * 2 + (size_t)BN * QN * 4;
  int nb = BN, qc = QN;
  while (nb > 1 && fixed + (size_t)nb * qc * KN * 2 > ws_size) nb >>= 1;
  while (qc > 128 && fixed + (size_t)nb * qc * KN * 2 > ws_size) qc >>= 1;

  prep<<<dim3((BN * QN * FN) / 2048, 4), 256, 0, stream>>>(qm, km, vm, qb, kb, Vt, sums);
  for (int b0 = 0; b0 < BN; b0 += nb) {
    for (int q0 = 0; q0 < QN; q0 += qc) {
      gemm_s<<<dim3(qc / 128, KN / 128, nb), 256, 0, stream>>>(qb, kb, Sws, sums,
                                                               attn, alibi, b0, q0, qc);
      softmax_w<<<dim3(qc, 1, nb), 256, 0, stream>>>(Sws, cq, ck, attn, alibi, bsp,
                                                     sums, b0, q0, qc);
      gemm_w<<<dim3(qc / 128, FVN / 128, nb), 256, 0, stream>>>(Sws, Vt, out, b0, q0, qc);
    }
  }
}